// Round 3
// baseline (351.713 us; speedup 1.0000x reference)
//
#include <hip/hip_runtime.h>
#include <hip/hip_bf16.h>
#include <math.h>

#define B_ 2
#define N_ 6
#define C_ 80
#define FH_ 16
#define FW_ 44
#define D_ 112
#define NX_ 128
#define NY_ 128
#define HW_ (FH_ * FW_)             /* 704 */
#define NCOL (B_ * N_ * HW_)        /* 8448 */
#define NCELL (B_ * NY_ * NX_)      /* 32768 */
#define MAXT (NCOL * D_)            /* 946176 tuple capacity */
#define GB_CELLS 16                 /* cells per gather block (1 wave each) */
#define NBB 256                     /* build blocks (33 column blocks + 223 transpose) */

typedef __hip_bfloat16 bf16;
typedef unsigned short u16;

__device__ __forceinline__ float loadf(const void* p, int i, int isbf) {
  if (isbf) return __bfloat162float(((const bf16*)p)[i]);
  return ((const float*)p)[i];
}

// ---------- adjugate 4x4 inverse: static indexing only (no scratch!) ----------
__device__ void inv4(const float m[16], float invOut[16]) {
  float inv[16];
  inv[0]  =  m[5]*m[10]*m[15] - m[5]*m[11]*m[14] - m[9]*m[6]*m[15] + m[9]*m[7]*m[14] + m[13]*m[6]*m[11] - m[13]*m[7]*m[10];
  inv[4]  = -m[4]*m[10]*m[15] + m[4]*m[11]*m[14] + m[8]*m[6]*m[15] - m[8]*m[7]*m[14] - m[12]*m[6]*m[11] + m[12]*m[7]*m[10];
  inv[8]  =  m[4]*m[9]*m[15]  - m[4]*m[11]*m[13] - m[8]*m[5]*m[15] + m[8]*m[7]*m[13] + m[12]*m[5]*m[11] - m[12]*m[7]*m[9];
  inv[12] = -m[4]*m[9]*m[14]  + m[4]*m[10]*m[13] + m[8]*m[5]*m[14] - m[8]*m[6]*m[13] - m[12]*m[5]*m[10] + m[12]*m[6]*m[9];
  inv[1]  = -m[1]*m[10]*m[15] + m[1]*m[11]*m[14] + m[9]*m[2]*m[15] - m[9]*m[3]*m[14] - m[13]*m[2]*m[11] + m[13]*m[3]*m[10];
  inv[5]  =  m[0]*m[10]*m[15] - m[0]*m[11]*m[14] - m[8]*m[2]*m[15] + m[8]*m[3]*m[14] + m[12]*m[2]*m[11] - m[12]*m[3]*m[10];
  inv[9]  = -m[0]*m[9]*m[15]  + m[0]*m[11]*m[13] + m[8]*m[1]*m[15] - m[8]*m[3]*m[13] - m[12]*m[1]*m[11] + m[12]*m[3]*m[9];
  inv[13] =  m[0]*m[9]*m[14]  - m[0]*m[10]*m[13] - m[8]*m[1]*m[14] + m[8]*m[2]*m[13] + m[12]*m[1]*m[10] - m[12]*m[2]*m[9];
  inv[2]  =  m[1]*m[6]*m[15]  - m[1]*m[7]*m[14]  - m[5]*m[2]*m[15] + m[5]*m[3]*m[14] + m[13]*m[2]*m[7]  - m[13]*m[3]*m[6];
  inv[6]  = -m[0]*m[6]*m[15]  + m[0]*m[7]*m[14]  + m[4]*m[2]*m[15] - m[4]*m[3]*m[14] - m[12]*m[2]*m[7]  + m[12]*m[3]*m[6];
  inv[10] =  m[0]*m[5]*m[15]  - m[0]*m[7]*m[13]  - m[4]*m[1]*m[15] + m[4]*m[3]*m[13] + m[12]*m[1]*m[7]  - m[12]*m[3]*m[5];
  inv[14] = -m[0]*m[5]*m[14]  + m[0]*m[6]*m[13]  + m[4]*m[1]*m[14] - m[4]*m[2]*m[13] - m[12]*m[1]*m[6]  + m[12]*m[2]*m[5];
  inv[3]  = -m[1]*m[6]*m[11]  + m[1]*m[7]*m[10]  + m[5]*m[2]*m[11] - m[5]*m[3]*m[10] - m[9]*m[2]*m[7]   + m[9]*m[3]*m[6];
  inv[7]  =  m[0]*m[6]*m[11]  - m[0]*m[7]*m[10]  - m[4]*m[2]*m[11] + m[4]*m[3]*m[10] + m[8]*m[2]*m[7]   - m[8]*m[3]*m[6];
  inv[11] = -m[0]*m[5]*m[11]  + m[0]*m[7]*m[9]   + m[4]*m[1]*m[11] - m[4]*m[3]*m[9]  - m[8]*m[1]*m[7]   + m[8]*m[3]*m[5];
  inv[15] =  m[0]*m[5]*m[10]  - m[0]*m[6]*m[9]   - m[4]*m[1]*m[10] + m[4]*m[2]*m[9]  + m[8]*m[1]*m[6]   - m[8]*m[2]*m[5];
  float det = m[0]*inv[0] + m[1]*inv[4] + m[2]*inv[8] + m[3]*inv[12];
  det = 1.0f / det;
  for (int i = 0; i < 16; i++) invOut[i] = inv[i] * det;
}

__device__ void mul4(const float A[16], const float Bm[16], float Cm[16]) {
  for (int i = 0; i < 4; i++)
    for (int j = 0; j < 4; j++) {
      float s = 0.f;
      for (int k = 0; k < 4; k++) s += A[i * 4 + k] * Bm[k * 4 + j];
      Cm[i * 4 + j] = s;
    }
}

// ---------- shared geometry (VERBATIM from verified baseline) ----------
__device__ __forceinline__ int geom_cell(const float* __restrict__ mats,
                                         int bn, int h, int w, int d) {
  const float* Ai = mats + bn * 32;
  const float* M = mats + bn * 32 + 16;
  float u = (float)w * (703.0f / 43.0f);
  float v = (float)h * 17.0f;
  float dep = 2.25f + 0.5f * (float)d;
  float p0 = ((Ai[0] * u + Ai[1] * v) + Ai[2] * dep) + Ai[3];
  float p1 = ((Ai[4] * u + Ai[5] * v) + Ai[6] * dep) + Ai[7];
  float p2 = ((Ai[8] * u + Ai[9] * v) + Ai[10] * dep) + Ai[11];
  float p3 = ((Ai[12] * u + Ai[13] * v) + Ai[14] * dep) + Ai[15];
  float q0 = p0 * p2, q1 = p1 * p2;
  float gx = ((M[0] * q0 + M[1] * q1) + M[2] * p2) + M[3] * p3;
  float gy = ((M[4] * q0 + M[5] * q1) + M[6] * p2) + M[7] * p3;
  float gz = ((M[8] * q0 + M[9] * q1) + M[10] * p2) + M[11] * p3;
  int ix = (int)floorf((gx + 51.2f) / 0.8f);
  int iy = (int)floorf((gy + 51.2f) / 0.8f);
  int iz = (int)floorf((gz + 5.0f) / 8.0f);
  bool valid = (ix >= 0) && (ix < NX_) && (iy >= 0) && (iy < NY_) && (iz == 0);
  int b = bn / N_;
  return valid ? (b * (NY_ * NX_) + iy * NX_ + ix) : -1;
}

// ---------- node 1: dtype detect + matrix fold + zero counts/done ----------
__global__ void lss_prep(const void* __restrict__ logits,
                         const void* __restrict__ s2e, const void* __restrict__ intrin,
                         const void* __restrict__ ida, const void* __restrict__ bda,
                         float* __restrict__ mats, int* __restrict__ flags,
                         int* __restrict__ counts, int* __restrict__ done) {
  __shared__ int s_cnt;
  __shared__ int s_mats_bf;
  const int t = threadIdx.x;
  if (t == 0) { s_cnt = 0; *done = 0; }
  __syncthreads();
  {
    const unsigned short* u = (const unsigned short*)logits;
    unsigned short v = u[2 * t];
    int e = (v >> 7) & 0xFF;
    if (v == 0 || (e >= 110 && e <= 136)) atomicAdd(&s_cnt, 1);
  }
  __syncthreads();
  if (t == 0) {
    flags[0] = (s_cnt > 170) ? 1 : 0;  // tensors bf16?
    float v = ((const float*)intrin)[0];
    s_mats_bf = (v > 100.f && v < 1.0e6f) ? 0 : 1;
    flags[1] = s_mats_bf;
  }
  __syncthreads();
  const int mbf = s_mats_bf;
  if (t < B_ * N_) {
    int b = t / N_;
    float S[16], I[16], A[16], Bd[16], Iinv[16], Ainv[16], Cm[16], M[16];
    for (int i = 0; i < 16; i++) {
      S[i]  = loadf(s2e,    t * 16 + i, mbf);
      I[i]  = loadf(intrin, t * 16 + i, mbf);
      A[i]  = loadf(ida,    t * 16 + i, mbf);
      Bd[i] = loadf(bda,    b * 16 + i, mbf);
    }
    inv4(I, Iinv);
    inv4(A, Ainv);
    mul4(S, Iinv, Cm);
    mul4(Bd, Cm, M);
    for (int i = 0; i < 16; i++) { mats[t * 32 + i] = Ainv[i]; mats[t * 32 + 16 + i] = M[i]; }
  }
  for (int i = t; i < NCELL; i += 256) counts[i] = 0;
}

// ---------- node 2: transpose + softmax + geometry + runs + counts + scan ----
// blocks 0..32: one column per thread (coalesced logits reads, geom ONCE,
//               in-thread run compression). blocks 33..255: ctx transpose.
// last block to finish performs the 32768-entry scan (order-independent).
__global__ __launch_bounds__(256) void lss_build(
    const void* __restrict__ ctx, const void* __restrict__ logits,
    const float* __restrict__ mats, const int* __restrict__ flags,
    int* __restrict__ counts, int* __restrict__ offsets, int* __restrict__ cursors,
    int* __restrict__ done, int* __restrict__ nrun,
    u16* __restrict__ runc, float* __restrict__ runw, float* __restrict__ ctx_t) {
  const int t = threadIdx.x;
  const int blk = blockIdx.x;
  const int tbf = flags[0];

  if (blk >= 33) {
    // ---- transpose: read-linear (coalesced), write-strided (L2-absorbed) ----
    for (int i = (blk - 33) * 256 + t; i < NCOL * C_; i += (NBB - 33) * 256) {
      int bn = i / (C_ * HW_);
      int r  = i - bn * (C_ * HW_);
      int c  = r / HW_;
      int hw = r - c * HW_;
      ctx_t[(bn * HW_ + hw) * C_ + c] = loadf(ctx, i, tbf);
    }
  } else {
    // ---- one full column per thread ----
    const int col = blk * 256 + t;          // 33*256 == NCOL exactly
    const int bn = col / HW_;
    const int hw = col - bn * HW_;
    const int h = hw / FW_, w = hw - h * FW_;
    const int base = bn * (D_ * HW_) + hw;  // consecutive threads -> consecutive addrs
    // pass 1: online softmax (max + rescaled sum)
    float m = -1e30f, s = 0.f;
    for (int d = 0; d < D_; ++d) {
      float l = loadf(logits, base + d * HW_, tbf);
      float nm = fmaxf(m, l);
      s = s * expf(m - nm) + expf(l - nm);
      m = nm;
    }
    const float inv_sum = 1.0f / s;
    // pass 2: weights + geometry (once) + run compression
    int prev = -1; float racc = 0.f; int nr = 0;
    for (int d = 0; d < D_; ++d) {
      float l = loadf(logits, base + d * HW_, tbf);
      float wgt = expf(l - m) * inv_sum;
      int cell = geom_cell(mats, bn, h, w, d);
      if (cell != prev) {
        if (prev >= 0) {
          runc[col * D_ + nr] = (u16)prev; runw[col * D_ + nr] = racc; ++nr;
          atomicAdd(&counts[prev], 1);
        }
        prev = cell; racc = wgt;
      } else {
        racc += wgt;
      }
    }
    if (prev >= 0) {
      runc[col * D_ + nr] = (u16)prev; runw[col * D_ + nr] = racc; ++nr;
      atomicAdd(&counts[prev], 1);
    }
    nrun[col] = nr;
  }

  // ---- last-block scan (any dispatch order is correct; no co-residency req) --
  __syncthreads();
  __shared__ int s_last;
  if (t == 0) {
    __threadfence();                         // release: counts atomics visible
    s_last = (atomicAdd(done, 1) == NBB - 1);
  }
  __syncthreads();
  if (!s_last) return;
  __threadfence();                           // acquire

  __shared__ int s_sum[256];
  const int cb = t * 128;
  int tot = 0;
  for (int j = 0; j < 128; ++j)
    tot += __hip_atomic_load(&counts[cb + j], __ATOMIC_RELAXED, __HIP_MEMORY_SCOPE_AGENT);
  s_sum[t] = tot;
  __syncthreads();
  for (int st = 1; st < 256; st <<= 1) {
    int v = (t >= st) ? s_sum[t - st] : 0;
    __syncthreads();
    s_sum[t] += v;
    __syncthreads();
  }
  int run = s_sum[t] - tot;                  // exclusive prefix for this 128-chunk
  for (int j = 0; j < 128; ++j) {
    int v = __hip_atomic_load(&counts[cb + j], __ATOMIC_RELAXED, __HIP_MEMORY_SCOPE_AGENT);
    offsets[cb + j] = run;
    cursors[cb + j] = run;
    run += v;
  }
}

// ---------- node 3: scatter runs -> CSR tuples (wave per column) ----------
__global__ __launch_bounds__(256) void lss_scatter(
    const int* __restrict__ nrun, const u16* __restrict__ runc,
    const float* __restrict__ runw, int* __restrict__ cursors,
    u16* __restrict__ colids, float* __restrict__ wts) {
  const int col = blockIdx.x * 4 + (threadIdx.x >> 6);
  const int ln = threadIdx.x & 63;
  if (col >= NCOL) return;
  const int nr = nrun[col];
  for (int r = ln; r < nr; r += 64) {
    int cell = runc[col * D_ + r];
    float wv = runw[col * D_ + r];
    int pos = atomicAdd(&cursors[cell], 1);
    colids[pos] = (u16)col;
    wts[pos] = wv;
  }
}

// ---------- node 4: gather (unchanged, verified) ----------
__global__ __launch_bounds__(1024) void lss_gather(
    const float* __restrict__ ctx_t, const int* __restrict__ counts,
    const int* __restrict__ offsets, const u16* __restrict__ colids,
    const float* __restrict__ wts, const int* __restrict__ flags,
    void* __restrict__ out) {
  __shared__ float s_out[GB_CELLS * 84];
  const int tid = threadIdx.x;
  const int wv = tid >> 6;          // local cell 0..15
  const int ln = tid & 63;
  const int sl = ln >> 2;           // j-slice 0..15
  const int g = ln & 3;             // channel quarter
  const int cell = blockIdx.x * GB_CELLS + wv;
  const int n = counts[cell];
  const int off = offsets[cell];

  float acc[20];
#pragma unroll
  for (int i = 0; i < 20; i++) acc[i] = 0.f;

  for (int j = sl; j < n; j += 16) {
    int colj = colids[off + j];
    float wj = wts[off + j];
    const float4* cp = (const float4*)(ctx_t + colj * C_ + g * 20);
#pragma unroll
    for (int q = 0; q < 5; q++) {
      float4 v = cp[q];
      acc[q * 4 + 0] += wj * v.x;
      acc[q * 4 + 1] += wj * v.y;
      acc[q * 4 + 2] += wj * v.z;
      acc[q * 4 + 3] += wj * v.w;
    }
  }
#pragma unroll
  for (int msk = 4; msk <= 32; msk <<= 1) {
#pragma unroll
    for (int i = 0; i < 20; i++) acc[i] += __shfl_xor(acc[i], msk);
  }
  if (sl == 0) {
#pragma unroll
    for (int i = 0; i < 20; i++) s_out[wv * 84 + g * 20 + i] = acc[i];
  }
  __syncthreads();

  const int x = tid & 15;
  const int c0 = tid >> 4;          // 0..63
  const int cell0 = blockIdx.x * GB_CELLS;
  const int b = cell0 >> 14;
  const int yx0 = cell0 & 16383;
  if (flags[0]) {
    bf16* o = (bf16*)out;
    o[(size_t)(b * C_ + c0) * (NY_ * NX_) + yx0 + x] = __float2bfloat16(s_out[x * 84 + c0]);
    if (c0 < 16)
      o[(size_t)(b * C_ + 64 + c0) * (NY_ * NX_) + yx0 + x] = __float2bfloat16(s_out[x * 84 + 64 + c0]);
  } else {
    float* o = (float*)out;
    o[(size_t)(b * C_ + c0) * (NY_ * NX_) + yx0 + x] = s_out[x * 84 + c0];
    if (c0 < 16)
      o[(size_t)(b * C_ + 64 + c0) * (NY_ * NX_) + yx0 + x] = s_out[x * 84 + 64 + c0];
  }
}

extern "C" void kernel_launch(void* const* d_in, const int* in_sizes, int n_in,
                              void* d_out, int out_size, void* d_ws, size_t ws_size,
                              hipStream_t stream) {
  const void* ctx = d_in[0];
  const void* logits = d_in[1];
  const void* s2e = d_in[2];
  const void* intrin = d_in[3];
  const void* ida = d_in[4];
  const void* bda = d_in[5];

  float* wsf = (float*)d_ws;
  int* flags   = (int*)wsf;                 // [0],[1] flags; [4] done
  int* done    = flags + 4;
  float* mats  = wsf + 16;                  // 384 floats used
  int* counts  = (int*)(wsf + 512);
  int* offsets = counts + NCELL;
  int* cursors = offsets + NCELL;
  int* nrun    = cursors + NCELL;           // 8448
  float* runw  = (float*)(nrun + NCOL);     // MAXT floats
  float* ctx_t = runw + MAXT;               // NCOL*C floats
  float* wts   = ctx_t + NCOL * C_;         // MAXT floats
  u16* colids  = (u16*)(wts + MAXT);        // MAXT u16
  u16* runc    = colids + MAXT;             // MAXT u16

  lss_prep<<<1, 256, 0, stream>>>(logits, s2e, intrin, ida, bda, mats, flags, counts, done);
  lss_build<<<NBB, 256, 0, stream>>>(ctx, logits, mats, flags, counts, offsets,
                                     cursors, done, nrun, runc, runw, ctx_t);
  lss_scatter<<<NCOL / 4, 256, 0, stream>>>(nrun, runc, runw, cursors, colids, wts);
  lss_gather<<<NCELL / GB_CELLS, 1024, 0, stream>>>(ctx_t, counts, offsets, colids, wts, flags, d_out);
}

// Round 4
// 283.117 us; speedup vs baseline: 1.2423x; 1.2423x over previous
//
#include <hip/hip_runtime.h>
#include <hip/hip_bf16.h>
#include <math.h>

#define B_ 2
#define N_ 6
#define C_ 80
#define FH_ 16
#define FW_ 44
#define D_ 112
#define NX_ 128
#define NY_ 128
#define HW_ (FH_ * FW_)             /* 704 */
#define NCOL (B_ * N_ * HW_)        /* 8448 */
#define NCELL (B_ * NY_ * NX_)      /* 32768 */
#define MAXT (NCOL * D_)            /* 946176 tuple capacity */
#define GB_CELLS 16                 /* cells per gather block (1 wave each) */
#define NCB 2112                    /* count blocks: 4 column-waves each -> 8448 cols */
#define NTB 224                     /* transpose blocks appended to count grid */

typedef __hip_bfloat16 bf16;
typedef unsigned short u16;

__device__ __forceinline__ float loadf(const void* p, int i, int isbf) {
  if (isbf) return __bfloat162float(((const bf16*)p)[i]);
  return ((const float*)p)[i];
}

// ---------- adjugate 4x4 inverse: static indexing only (no scratch!) ----------
__device__ void inv4(const float m[16], float invOut[16]) {
  float inv[16];
  inv[0]  =  m[5]*m[10]*m[15] - m[5]*m[11]*m[14] - m[9]*m[6]*m[15] + m[9]*m[7]*m[14] + m[13]*m[6]*m[11] - m[13]*m[7]*m[10];
  inv[4]  = -m[4]*m[10]*m[15] + m[4]*m[11]*m[14] + m[8]*m[6]*m[15] - m[8]*m[7]*m[14] - m[12]*m[6]*m[11] + m[12]*m[7]*m[10];
  inv[8]  =  m[4]*m[9]*m[15]  - m[4]*m[11]*m[13] - m[8]*m[5]*m[15] + m[8]*m[7]*m[13] + m[12]*m[5]*m[11] - m[12]*m[7]*m[9];
  inv[12] = -m[4]*m[9]*m[14]  + m[4]*m[10]*m[13] + m[8]*m[5]*m[14] - m[8]*m[6]*m[13] - m[12]*m[5]*m[10] + m[12]*m[6]*m[9];
  inv[1]  = -m[1]*m[10]*m[15] + m[1]*m[11]*m[14] + m[9]*m[2]*m[15] - m[9]*m[3]*m[14] - m[13]*m[2]*m[11] + m[13]*m[3]*m[10];
  inv[5]  =  m[0]*m[10]*m[15] - m[0]*m[11]*m[14] - m[8]*m[2]*m[15] + m[8]*m[3]*m[14] + m[12]*m[2]*m[11] - m[12]*m[3]*m[10];
  inv[9]  = -m[0]*m[9]*m[15]  + m[0]*m[11]*m[13] + m[8]*m[1]*m[15] - m[8]*m[3]*m[13] - m[12]*m[1]*m[11] + m[12]*m[3]*m[9];
  inv[13] =  m[0]*m[9]*m[14]  - m[0]*m[10]*m[13] - m[8]*m[1]*m[14] + m[8]*m[2]*m[13] + m[12]*m[1]*m[10] - m[12]*m[2]*m[9];
  inv[2]  =  m[1]*m[6]*m[15]  - m[1]*m[7]*m[14]  - m[5]*m[2]*m[15] + m[5]*m[3]*m[14] + m[13]*m[2]*m[7]  - m[13]*m[3]*m[6];
  inv[6]  = -m[0]*m[6]*m[15]  + m[0]*m[7]*m[14]  + m[4]*m[2]*m[15] - m[4]*m[3]*m[14] - m[12]*m[2]*m[7]  + m[12]*m[3]*m[6];
  inv[10] =  m[0]*m[5]*m[15]  - m[0]*m[7]*m[13]  - m[4]*m[1]*m[15] + m[4]*m[3]*m[13] + m[12]*m[1]*m[7]  - m[12]*m[3]*m[5];
  inv[14] = -m[0]*m[5]*m[14]  + m[0]*m[6]*m[13]  + m[4]*m[1]*m[14] - m[4]*m[2]*m[13] - m[12]*m[1]*m[6]  + m[12]*m[2]*m[5];
  inv[3]  = -m[1]*m[6]*m[11]  + m[1]*m[7]*m[10]  + m[5]*m[2]*m[11] - m[5]*m[3]*m[10] - m[9]*m[2]*m[7]   + m[9]*m[3]*m[6];
  inv[7]  =  m[0]*m[6]*m[11]  - m[0]*m[7]*m[10]  - m[4]*m[2]*m[11] + m[4]*m[3]*m[10] + m[8]*m[2]*m[7]   - m[8]*m[3]*m[6];
  inv[11] = -m[0]*m[5]*m[11]  + m[0]*m[7]*m[9]   + m[4]*m[1]*m[11] - m[4]*m[3]*m[9]  - m[8]*m[1]*m[7]   + m[8]*m[3]*m[5];
  inv[15] =  m[0]*m[5]*m[10]  - m[0]*m[6]*m[9]   - m[4]*m[1]*m[10] + m[4]*m[2]*m[9]  + m[8]*m[1]*m[6]   - m[8]*m[2]*m[5];
  float det = m[0]*inv[0] + m[1]*inv[4] + m[2]*inv[8] + m[3]*inv[12];
  det = 1.0f / det;
  for (int i = 0; i < 16; i++) invOut[i] = inv[i] * det;
}

__device__ void mul4(const float A[16], const float Bm[16], float Cm[16]) {
  for (int i = 0; i < 4; i++)
    for (int j = 0; j < 4; j++) {
      float s = 0.f;
      for (int k = 0; k < 4; k++) s += A[i * 4 + k] * Bm[k * 4 + j];
      Cm[i * 4 + j] = s;
    }
}

// ---------- shared geometry (VERBATIM, verified) ----------
__device__ __forceinline__ int geom_cell(const float* __restrict__ mats,
                                         int bn, int h, int w, int d) {
  const float* Ai = mats + bn * 32;
  const float* M = mats + bn * 32 + 16;
  float u = (float)w * (703.0f / 43.0f);
  float v = (float)h * 17.0f;
  float dep = 2.25f + 0.5f * (float)d;
  float p0 = ((Ai[0] * u + Ai[1] * v) + Ai[2] * dep) + Ai[3];
  float p1 = ((Ai[4] * u + Ai[5] * v) + Ai[6] * dep) + Ai[7];
  float p2 = ((Ai[8] * u + Ai[9] * v) + Ai[10] * dep) + Ai[11];
  float p3 = ((Ai[12] * u + Ai[13] * v) + Ai[14] * dep) + Ai[15];
  float q0 = p0 * p2, q1 = p1 * p2;
  float gx = ((M[0] * q0 + M[1] * q1) + M[2] * p2) + M[3] * p3;
  float gy = ((M[4] * q0 + M[5] * q1) + M[6] * p2) + M[7] * p3;
  float gz = ((M[8] * q0 + M[9] * q1) + M[10] * p2) + M[11] * p3;
  int ix = (int)floorf((gx + 51.2f) / 0.8f);
  int iy = (int)floorf((gy + 51.2f) / 0.8f);
  int iz = (int)floorf((gz + 5.0f) / 8.0f);
  bool valid = (ix >= 0) && (ix < NX_) && (iy >= 0) && (iy < NY_) && (iz == 0);
  int b = bn / N_;
  return valid ? (b * (NY_ * NX_) + iy * NX_ + ix) : -1;
}

// ---------- node 1: flags + mats (block 0) + distributed zero ----------
__global__ __launch_bounds__(256) void lss_prep(
    const void* __restrict__ logits,
    const void* __restrict__ s2e, const void* __restrict__ intrin,
    const void* __restrict__ ida, const void* __restrict__ bda,
    float* __restrict__ mats, int* __restrict__ flags,
    int* __restrict__ counts, int* __restrict__ done) {
  const int t = threadIdx.x;
  const int blk = blockIdx.x;
  // all blocks: zero their slice of counts (33*256 = 8448 -> 4 iters)
  for (int i = blk * 256 + t; i < NCELL; i += 33 * 256) counts[i] = 0;
  if (blk != 0) return;

  __shared__ int s_cnt;
  __shared__ int s_mats_bf;
  if (t == 0) { s_cnt = 0; *done = 0; }
  __syncthreads();
  {
    const unsigned short* u = (const unsigned short*)logits;
    unsigned short v = u[2 * t];
    int e = (v >> 7) & 0xFF;
    if (v == 0 || (e >= 110 && e <= 136)) atomicAdd(&s_cnt, 1);
  }
  __syncthreads();
  if (t == 0) {
    flags[0] = (s_cnt > 170) ? 1 : 0;  // tensors bf16?
    float v = ((const float*)intrin)[0];
    s_mats_bf = (v > 100.f && v < 1.0e6f) ? 0 : 1;
    flags[1] = s_mats_bf;
  }
  __syncthreads();
  const int mbf = s_mats_bf;
  if (t < B_ * N_) {
    int b = t / N_;
    float S[16], I[16], A[16], Bd[16], Iinv[16], Ainv[16], Cm[16], M[16];
    for (int i = 0; i < 16; i++) {
      S[i]  = loadf(s2e,    t * 16 + i, mbf);
      I[i]  = loadf(intrin, t * 16 + i, mbf);
      A[i]  = loadf(ida,    t * 16 + i, mbf);
      Bd[i] = loadf(bda,    b * 16 + i, mbf);
    }
    inv4(I, Iinv);
    inv4(A, Ainv);
    mul4(S, Iinv, Cm);
    mul4(Bd, Cm, M);
    for (int i = 0; i < 16; i++) { mats[t * 32 + i] = Ainv[i]; mats[t * 32 + 16 + i] = M[i]; }
  }
}

// ---------- node 2: count (wave/column, shuffle run heads) + transpose
//                    + last-block scan -> offsets/cursors ----------
__global__ __launch_bounds__(256) void lss_count(
    const void* __restrict__ ctx, const float* __restrict__ mats,
    const int* __restrict__ flags, int* __restrict__ counts,
    int* __restrict__ offsets, int* __restrict__ cursors,
    int* __restrict__ done, float* __restrict__ ctx_t) {
  const int t = threadIdx.x;
  const int blk = blockIdx.x;

  if (blk >= NCB) {
    // ---- transpose (overlapped with count): read-linear, write-strided ----
    const int tbf = flags[0];
    for (int i = (blk - NCB) * 256 + t; i < NCOL * C_; i += NTB * 256) {
      int bn = i / (C_ * HW_);
      int r  = i - bn * (C_ * HW_);
      int c  = r / HW_;
      int hw = r - c * HW_;
      ctx_t[(bn * HW_ + hw) * C_ + c] = loadf(ctx, i, tbf);
    }
    return;  // transpose blocks do not participate in done-counter
  }

  // ---- 4 column-waves per block (verified round-1 shuffle logic) ----
  {
    const int col = blk * 4 + (t >> 6);
    const int ln = t & 63;
    const int w = col % FW_;
    const int h = (col / FW_) % FH_;
    const int bn = col / (FW_ * FH_);
    int c0 = geom_cell(mats, bn, h, w, ln);
    int c1 = (ln < D_ - 64) ? geom_cell(mats, bn, h, w, ln + 64) : -3;
    int p0 = __shfl_up(c0, 1);          // cell(d-1) for d=ln
    int p1 = __shfl_up(c1, 1);          // cell(d-1) for d=ln+64 (ln>=1)
    int c63 = __shfl(c0, 63);           // cell(63) — predecessor of d=64
    if (ln == 0) p1 = c63;
    if (c0 >= 0 && (ln == 0 || p0 != c0)) atomicAdd(&counts[c0], 1);
    if (c1 >= 0 && p1 != c1) atomicAdd(&counts[c1], 1);
  }

  // ---- last-block scan (verified round-3 pattern) ----
  __syncthreads();
  __shared__ int s_last;
  if (t == 0) {
    __threadfence();                         // release: counts atomics visible
    s_last = (atomicAdd(done, 1) == NCB - 1);
  }
  __syncthreads();
  if (!s_last) return;
  __threadfence();                           // acquire

  __shared__ int s_sum[256];
  const int cb = t * 128;
  int tot = 0;
  for (int j = 0; j < 128; ++j)
    tot += __hip_atomic_load(&counts[cb + j], __ATOMIC_RELAXED, __HIP_MEMORY_SCOPE_AGENT);
  s_sum[t] = tot;
  __syncthreads();
  for (int st = 1; st < 256; st <<= 1) {
    int v = (t >= st) ? s_sum[t - st] : 0;
    __syncthreads();
    s_sum[t] += v;
    __syncthreads();
  }
  int run = s_sum[t] - tot;                  // exclusive prefix for this 128-chunk
  for (int j = 0; j < 128; ++j) {
    int v = __hip_atomic_load(&counts[cb + j], __ATOMIC_RELAXED, __HIP_MEMORY_SCOPE_AGENT);
    offsets[cb + j] = run;
    cursors[cb + j] = run;
    run += v;
  }
}

// ---------- node 3: fill (VERBATIM round-0 baseline, verified) ----------
__global__ __launch_bounds__(64) void lss_fill(
    const void* __restrict__ logits, const float* __restrict__ mats,
    const int* __restrict__ flags, int* __restrict__ cursors,
    u16* __restrict__ colids, float* __restrict__ wts) {
  const int tid = threadIdx.x;
  const int col = blockIdx.x;
  const int w = col % FW_;
  const int h = (col / FW_) % FH_;
  const int bn = col / (FW_ * FH_);
  const int tbf = flags[0];

  __shared__ float s_w[D_];
  __shared__ int s_cell[D_];

  const int base = ((bn * D_) * FH_ + h) * FW_ + w;
  float l0 = loadf(logits, base + tid * (FH_ * FW_), tbf);
  float l1 = (tid < D_ - 64) ? loadf(logits, base + (tid + 64) * (FH_ * FW_), tbf) : -1e30f;
  float m = fmaxf(l0, l1);
  for (int s = 32; s > 0; s >>= 1) m = fmaxf(m, __shfl_xor(m, s));
  float e0 = expf(l0 - m);
  float e1 = (tid < D_ - 64) ? expf(l1 - m) : 0.f;
  float sum = e0 + e1;
  for (int s = 32; s > 0; s >>= 1) sum += __shfl_xor(sum, s);
  float inv_sum = 1.0f / sum;

  s_w[tid] = e0;
  s_cell[tid] = geom_cell(mats, bn, h, w, tid);
  if (tid < D_ - 64) {
    s_w[tid + 64] = e1;
    s_cell[tid + 64] = geom_cell(mats, bn, h, w, tid + 64);
  }
  __syncthreads();

  for (int d = tid; d < D_; d += 64) {
    int vcell = s_cell[d];
    if (vcell >= 0 && (d == 0 || s_cell[d - 1] != vcell)) {
      float acc = s_w[d];
      for (int j = d + 1; j < D_ && s_cell[j] == vcell; ++j) acc += s_w[j];
      int pos = atomicAdd(&cursors[vcell], 1);
      colids[pos] = (u16)col;
      wts[pos] = acc * inv_sum;
    }
  }
}

// ---------- node 4: gather (VERBATIM, verified) ----------
__global__ __launch_bounds__(1024) void lss_gather(
    const float* __restrict__ ctx_t, const int* __restrict__ counts,
    const int* __restrict__ offsets, const u16* __restrict__ colids,
    const float* __restrict__ wts, const int* __restrict__ flags,
    void* __restrict__ out) {
  __shared__ float s_out[GB_CELLS * 84];
  const int tid = threadIdx.x;
  const int wv = tid >> 6;          // local cell 0..15
  const int ln = tid & 63;
  const int sl = ln >> 2;           // j-slice 0..15
  const int g = ln & 3;             // channel quarter
  const int cell = blockIdx.x * GB_CELLS + wv;
  const int n = counts[cell];
  const int off = offsets[cell];

  float acc[20];
#pragma unroll
  for (int i = 0; i < 20; i++) acc[i] = 0.f;

  for (int j = sl; j < n; j += 16) {
    int colj = colids[off + j];
    float wj = wts[off + j];
    const float4* cp = (const float4*)(ctx_t + colj * C_ + g * 20);
#pragma unroll
    for (int q = 0; q < 5; q++) {
      float4 v = cp[q];
      acc[q * 4 + 0] += wj * v.x;
      acc[q * 4 + 1] += wj * v.y;
      acc[q * 4 + 2] += wj * v.z;
      acc[q * 4 + 3] += wj * v.w;
    }
  }
#pragma unroll
  for (int msk = 4; msk <= 32; msk <<= 1) {
#pragma unroll
    for (int i = 0; i < 20; i++) acc[i] += __shfl_xor(acc[i], msk);
  }
  if (sl == 0) {
#pragma unroll
    for (int i = 0; i < 20; i++) s_out[wv * 84 + g * 20 + i] = acc[i];
  }
  __syncthreads();

  const int x = tid & 15;
  const int c0 = tid >> 4;          // 0..63
  const int cell0 = blockIdx.x * GB_CELLS;
  const int b = cell0 >> 14;
  const int yx0 = cell0 & 16383;
  if (flags[0]) {
    bf16* o = (bf16*)out;
    o[(size_t)(b * C_ + c0) * (NY_ * NX_) + yx0 + x] = __float2bfloat16(s_out[x * 84 + c0]);
    if (c0 < 16)
      o[(size_t)(b * C_ + 64 + c0) * (NY_ * NX_) + yx0 + x] = __float2bfloat16(s_out[x * 84 + 64 + c0]);
  } else {
    float* o = (float*)out;
    o[(size_t)(b * C_ + c0) * (NY_ * NX_) + yx0 + x] = s_out[x * 84 + c0];
    if (c0 < 16)
      o[(size_t)(b * C_ + 64 + c0) * (NY_ * NX_) + yx0 + x] = s_out[x * 84 + 64 + c0];
  }
}

extern "C" void kernel_launch(void* const* d_in, const int* in_sizes, int n_in,
                              void* d_out, int out_size, void* d_ws, size_t ws_size,
                              hipStream_t stream) {
  const void* ctx = d_in[0];
  const void* logits = d_in[1];
  const void* s2e = d_in[2];
  const void* intrin = d_in[3];
  const void* ida = d_in[4];
  const void* bda = d_in[5];

  float* wsf = (float*)d_ws;
  int* flags   = (int*)wsf;                 // [0],[1] flags; [4] done
  int* done    = flags + 4;
  float* mats  = wsf + 16;                  // 384 floats used
  int* counts  = (int*)(wsf + 512);
  int* offsets = counts + NCELL;
  int* cursors = offsets + NCELL;
  float* ctx_t = (float*)(cursors + NCELL); // NCOL*C floats
  float* wts   = ctx_t + NCOL * C_;         // MAXT floats
  u16* colids  = (u16*)(wts + MAXT);        // MAXT u16

  lss_prep<<<33, 256, 0, stream>>>(logits, s2e, intrin, ida, bda, mats, flags, counts, done);
  lss_count<<<NCB + NTB, 256, 0, stream>>>(ctx, mats, flags, counts, offsets,
                                           cursors, done, ctx_t);
  lss_fill<<<NCOL, 64, 0, stream>>>(logits, mats, flags, cursors, colids, wts);
  lss_gather<<<NCELL / GB_CELLS, 1024, 0, stream>>>(ctx_t, counts, offsets, colids, wts, flags, d_out);
}

// Round 5
// 178.216 us; speedup vs baseline: 1.9735x; 1.5886x over previous
//
#include <hip/hip_runtime.h>
#include <hip/hip_bf16.h>
#include <math.h>

#define B_ 2
#define N_ 6
#define C_ 80
#define FH_ 16
#define FW_ 44
#define D_ 112
#define NX_ 128
#define NY_ 128
#define HW_ (FH_ * FW_)             /* 704 */
#define NCOL (B_ * N_ * HW_)        /* 8448 */
#define NCELL (B_ * NY_ * NX_)      /* 32768 */
#define MAXT (NCOL * D_)            /* 946176 tuple capacity */
#define GB_CELLS 16                 /* cells per gather block (1 wave each) */
#define NCB 2112                    /* count blocks: 4 column-waves each -> 8448 cols */
#define NTB 2640                    /* transpose blocks: 1 elem/thread, NCOL*C/256 */

typedef __hip_bfloat16 bf16;
typedef unsigned short u16;

__device__ __forceinline__ float loadf(const void* p, int i, int isbf) {
  if (isbf) return __bfloat162float(((const bf16*)p)[i]);
  return ((const float*)p)[i];
}

// ---------- adjugate 4x4 inverse: static indexing only (no scratch!) ----------
__device__ void inv4(const float m[16], float invOut[16]) {
  float inv[16];
  inv[0]  =  m[5]*m[10]*m[15] - m[5]*m[11]*m[14] - m[9]*m[6]*m[15] + m[9]*m[7]*m[14] + m[13]*m[6]*m[11] - m[13]*m[7]*m[10];
  inv[4]  = -m[4]*m[10]*m[15] + m[4]*m[11]*m[14] + m[8]*m[6]*m[15] - m[8]*m[7]*m[14] - m[12]*m[6]*m[11] + m[12]*m[7]*m[10];
  inv[8]  =  m[4]*m[9]*m[15]  - m[4]*m[11]*m[13] - m[8]*m[5]*m[15] + m[8]*m[7]*m[13] + m[12]*m[5]*m[11] - m[12]*m[7]*m[9];
  inv[12] = -m[4]*m[9]*m[14]  + m[4]*m[10]*m[13] + m[8]*m[5]*m[14] - m[8]*m[6]*m[13] - m[12]*m[5]*m[10] + m[12]*m[6]*m[9];
  inv[1]  = -m[1]*m[10]*m[15] + m[1]*m[11]*m[14] + m[9]*m[2]*m[15] - m[9]*m[3]*m[14] - m[13]*m[2]*m[11] + m[13]*m[3]*m[10];
  inv[5]  =  m[0]*m[10]*m[15] - m[0]*m[11]*m[14] - m[8]*m[2]*m[15] + m[8]*m[3]*m[14] + m[12]*m[2]*m[11] - m[12]*m[3]*m[10];
  inv[9]  = -m[0]*m[9]*m[15]  + m[0]*m[11]*m[13] + m[8]*m[1]*m[15] - m[8]*m[3]*m[13] - m[12]*m[1]*m[11] + m[12]*m[3]*m[9];
  inv[13] =  m[0]*m[9]*m[14]  - m[0]*m[10]*m[13] - m[8]*m[1]*m[14] + m[8]*m[2]*m[13] + m[12]*m[1]*m[10] - m[12]*m[2]*m[9];
  inv[2]  =  m[1]*m[6]*m[15]  - m[1]*m[7]*m[14]  - m[5]*m[2]*m[15] + m[5]*m[3]*m[14] + m[13]*m[2]*m[7]  - m[13]*m[3]*m[6];
  inv[6]  = -m[0]*m[6]*m[15]  + m[0]*m[7]*m[14]  + m[4]*m[2]*m[15] - m[4]*m[3]*m[14] - m[12]*m[2]*m[7]  + m[12]*m[3]*m[6];
  inv[10] =  m[0]*m[5]*m[15]  - m[0]*m[7]*m[13]  - m[4]*m[1]*m[15] + m[4]*m[3]*m[13] + m[12]*m[1]*m[7]  - m[12]*m[3]*m[5];
  inv[14] = -m[0]*m[5]*m[14]  + m[0]*m[6]*m[13]  + m[4]*m[1]*m[14] - m[4]*m[2]*m[13] - m[12]*m[1]*m[6]  + m[12]*m[2]*m[5];
  inv[3]  = -m[1]*m[6]*m[11]  + m[1]*m[7]*m[10]  + m[5]*m[2]*m[11] - m[5]*m[3]*m[10] - m[9]*m[2]*m[7]   + m[9]*m[3]*m[6];
  inv[7]  =  m[0]*m[6]*m[11]  - m[0]*m[7]*m[10]  - m[4]*m[2]*m[11] + m[4]*m[3]*m[10] + m[8]*m[2]*m[7]   - m[8]*m[3]*m[6];
  inv[11] = -m[0]*m[5]*m[11]  + m[0]*m[7]*m[9]   + m[4]*m[1]*m[11] - m[4]*m[3]*m[9]  - m[8]*m[1]*m[7]   + m[8]*m[3]*m[5];
  inv[15] =  m[0]*m[5]*m[10]  - m[0]*m[6]*m[9]   - m[4]*m[1]*m[10] + m[4]*m[2]*m[9]  + m[8]*m[1]*m[6]   - m[8]*m[2]*m[5];
  float det = m[0]*inv[0] + m[1]*inv[4] + m[2]*inv[8] + m[3]*inv[12];
  det = 1.0f / det;
  for (int i = 0; i < 16; i++) invOut[i] = inv[i] * det;
}

__device__ void mul4(const float A[16], const float Bm[16], float Cm[16]) {
  for (int i = 0; i < 4; i++)
    for (int j = 0; j < 4; j++) {
      float s = 0.f;
      for (int k = 0; k < 4; k++) s += A[i * 4 + k] * Bm[k * 4 + j];
      Cm[i * 4 + j] = s;
    }
}

// ---------- shared geometry (VERBATIM, verified) ----------
__device__ __forceinline__ int geom_cell(const float* __restrict__ mats,
                                         int bn, int h, int w, int d) {
  const float* Ai = mats + bn * 32;
  const float* M = mats + bn * 32 + 16;
  float u = (float)w * (703.0f / 43.0f);
  float v = (float)h * 17.0f;
  float dep = 2.25f + 0.5f * (float)d;
  float p0 = ((Ai[0] * u + Ai[1] * v) + Ai[2] * dep) + Ai[3];
  float p1 = ((Ai[4] * u + Ai[5] * v) + Ai[6] * dep) + Ai[7];
  float p2 = ((Ai[8] * u + Ai[9] * v) + Ai[10] * dep) + Ai[11];
  float p3 = ((Ai[12] * u + Ai[13] * v) + Ai[14] * dep) + Ai[15];
  float q0 = p0 * p2, q1 = p1 * p2;
  float gx = ((M[0] * q0 + M[1] * q1) + M[2] * p2) + M[3] * p3;
  float gy = ((M[4] * q0 + M[5] * q1) + M[6] * p2) + M[7] * p3;
  float gz = ((M[8] * q0 + M[9] * q1) + M[10] * p2) + M[11] * p3;
  int ix = (int)floorf((gx + 51.2f) / 0.8f);
  int iy = (int)floorf((gy + 51.2f) / 0.8f);
  int iz = (int)floorf((gz + 5.0f) / 8.0f);
  bool valid = (ix >= 0) && (ix < NX_) && (iy >= 0) && (iy < NY_) && (iz == 0);
  int b = bn / N_;
  return valid ? (b * (NY_ * NX_) + iy * NX_ + ix) : -1;
}

// ---------- node 1: flags + mats (block 0) + distributed zero of counts ----
__global__ __launch_bounds__(256) void lss_prep(
    const void* __restrict__ logits,
    const void* __restrict__ s2e, const void* __restrict__ intrin,
    const void* __restrict__ ida, const void* __restrict__ bda,
    float* __restrict__ mats, int* __restrict__ flags,
    int* __restrict__ counts) {
  const int t = threadIdx.x;
  const int blk = blockIdx.x;
  for (int i = blk * 256 + t; i < NCELL; i += 33 * 256) counts[i] = 0;
  if (blk != 0) return;

  __shared__ int s_cnt;
  __shared__ int s_mats_bf;
  if (t == 0) s_cnt = 0;
  __syncthreads();
  {
    const unsigned short* u = (const unsigned short*)logits;
    unsigned short v = u[2 * t];
    int e = (v >> 7) & 0xFF;
    if (v == 0 || (e >= 110 && e <= 136)) atomicAdd(&s_cnt, 1);
  }
  __syncthreads();
  if (t == 0) {
    flags[0] = (s_cnt > 170) ? 1 : 0;  // tensors bf16?
    float v = ((const float*)intrin)[0];
    s_mats_bf = (v > 100.f && v < 1.0e6f) ? 0 : 1;
    flags[1] = s_mats_bf;
  }
  __syncthreads();
  const int mbf = s_mats_bf;
  if (t < B_ * N_) {
    int b = t / N_;
    float S[16], I[16], A[16], Bd[16], Iinv[16], Ainv[16], Cm[16], M[16];
    for (int i = 0; i < 16; i++) {
      S[i]  = loadf(s2e,    t * 16 + i, mbf);
      I[i]  = loadf(intrin, t * 16 + i, mbf);
      A[i]  = loadf(ida,    t * 16 + i, mbf);
      Bd[i] = loadf(bda,    b * 16 + i, mbf);
    }
    inv4(I, Iinv);
    inv4(A, Ainv);
    mul4(S, Iinv, Cm);
    mul4(Bd, Cm, M);
    for (int i = 0; i < 16; i++) { mats[t * 32 + i] = Ainv[i]; mats[t * 32 + 16 + i] = M[i]; }
  }
}

// ---------- node 2: count (4 column-waves/block) + transpose (r0 orientation)
// No scan tail, no done counter — those were the 145us latency island in r4.
__global__ __launch_bounds__(256) void lss_count(
    const void* __restrict__ ctx, const float* __restrict__ mats,
    const int* __restrict__ flags, int* __restrict__ counts,
    float* __restrict__ ctx_t) {
  const int t = threadIdx.x;
  const int blk = blockIdx.x;

  if (blk >= NCB) {
    // ---- transpose, round-0 verified orientation: strided read, linear write
    const int tbf = flags[0];
    const int i = (blk - NCB) * 256 + t;     // NTB*256 == NCOL*C exactly
    int col = i / C_, c = i - col * C_;
    int bn = col / HW_, r = col - bn * HW_;
    int h = r / FW_, w = r - h * FW_;
    ctx_t[i] = loadf(ctx, ((bn * C_ + c) * FH_ + h) * FW_ + w, tbf);
    return;
  }

  // ---- 4 column-waves per block (shuffle run-head count, verified) ----
  const int col = blk * 4 + (t >> 6);
  const int ln = t & 63;
  const int w = col % FW_;
  const int h = (col / FW_) % FH_;
  const int bn = col / (FW_ * FH_);
  int c0 = geom_cell(mats, bn, h, w, ln);
  int c1 = (ln < D_ - 64) ? geom_cell(mats, bn, h, w, ln + 64) : -3;
  int p0 = __shfl_up(c0, 1);          // cell(d-1) for d=ln
  int p1 = __shfl_up(c1, 1);          // cell(d-1) for d=ln+64 (ln>=1)
  int c63 = __shfl(c0, 63);           // cell(63) — predecessor of d=64
  if (ln == 0) p1 = c63;
  if (c0 >= 0 && (ln == 0 || p0 != c0)) atomicAdd(&counts[c0], 1);
  if (c1 >= 0 && p1 != c1) atomicAdd(&counts[c1], 1);
}

// ---------- node 3: exclusive scan of 32768 counts (r0 verbatim, verified) --
__global__ __launch_bounds__(1024) void lss_scan(const int* __restrict__ counts,
                                                 int* __restrict__ offsets,
                                                 int* __restrict__ cursors) {
  __shared__ int s[1024];
  const int t = threadIdx.x;
  const int base = t * 32;
  int local[32];
  int sum = 0;
  for (int j = 0; j < 32; j++) { local[j] = counts[base + j]; sum += local[j]; }
  s[t] = sum;
  __syncthreads();
  for (int st = 1; st < 1024; st <<= 1) {
    int v = (t >= st) ? s[t - st] : 0;
    __syncthreads();
    s[t] += v;
    __syncthreads();
  }
  int run = s[t] - sum;
  for (int j = 0; j < 32; j++) {
    offsets[base + j] = run;
    cursors[base + j] = run;
    run += local[j];
  }
}

// ---------- node 4: fill (round-0 verbatim, verified) ----------
__global__ __launch_bounds__(64) void lss_fill(
    const void* __restrict__ logits, const float* __restrict__ mats,
    const int* __restrict__ flags, int* __restrict__ cursors,
    u16* __restrict__ colids, float* __restrict__ wts) {
  const int tid = threadIdx.x;
  const int col = blockIdx.x;
  const int w = col % FW_;
  const int h = (col / FW_) % FH_;
  const int bn = col / (FW_ * FH_);
  const int tbf = flags[0];

  __shared__ float s_w[D_];
  __shared__ int s_cell[D_];

  const int base = ((bn * D_) * FH_ + h) * FW_ + w;
  float l0 = loadf(logits, base + tid * (FH_ * FW_), tbf);
  float l1 = (tid < D_ - 64) ? loadf(logits, base + (tid + 64) * (FH_ * FW_), tbf) : -1e30f;
  float m = fmaxf(l0, l1);
  for (int s = 32; s > 0; s >>= 1) m = fmaxf(m, __shfl_xor(m, s));
  float e0 = expf(l0 - m);
  float e1 = (tid < D_ - 64) ? expf(l1 - m) : 0.f;
  float sum = e0 + e1;
  for (int s = 32; s > 0; s >>= 1) sum += __shfl_xor(sum, s);
  float inv_sum = 1.0f / sum;

  s_w[tid] = e0;
  s_cell[tid] = geom_cell(mats, bn, h, w, tid);
  if (tid < D_ - 64) {
    s_w[tid + 64] = e1;
    s_cell[tid + 64] = geom_cell(mats, bn, h, w, tid + 64);
  }
  __syncthreads();

  for (int d = tid; d < D_; d += 64) {
    int vcell = s_cell[d];
    if (vcell >= 0 && (d == 0 || s_cell[d - 1] != vcell)) {
      float acc = s_w[d];
      for (int j = d + 1; j < D_ && s_cell[j] == vcell; ++j) acc += s_w[j];
      int pos = atomicAdd(&cursors[vcell], 1);
      colids[pos] = (u16)col;
      wts[pos] = acc * inv_sum;
    }
  }
}

// ---------- node 5: gather (verbatim, verified) ----------
__global__ __launch_bounds__(1024) void lss_gather(
    const float* __restrict__ ctx_t, const int* __restrict__ counts,
    const int* __restrict__ offsets, const u16* __restrict__ colids,
    const float* __restrict__ wts, const int* __restrict__ flags,
    void* __restrict__ out) {
  __shared__ float s_out[GB_CELLS * 84];
  const int tid = threadIdx.x;
  const int wv = tid >> 6;          // local cell 0..15
  const int ln = tid & 63;
  const int sl = ln >> 2;           // j-slice 0..15
  const int g = ln & 3;             // channel quarter
  const int cell = blockIdx.x * GB_CELLS + wv;
  const int n = counts[cell];
  const int off = offsets[cell];

  float acc[20];
#pragma unroll
  for (int i = 0; i < 20; i++) acc[i] = 0.f;

  for (int j = sl; j < n; j += 16) {
    int colj = colids[off + j];
    float wj = wts[off + j];
    const float4* cp = (const float4*)(ctx_t + colj * C_ + g * 20);
#pragma unroll
    for (int q = 0; q < 5; q++) {
      float4 v = cp[q];
      acc[q * 4 + 0] += wj * v.x;
      acc[q * 4 + 1] += wj * v.y;
      acc[q * 4 + 2] += wj * v.z;
      acc[q * 4 + 3] += wj * v.w;
    }
  }
#pragma unroll
  for (int msk = 4; msk <= 32; msk <<= 1) {
#pragma unroll
    for (int i = 0; i < 20; i++) acc[i] += __shfl_xor(acc[i], msk);
  }
  if (sl == 0) {
#pragma unroll
    for (int i = 0; i < 20; i++) s_out[wv * 84 + g * 20 + i] = acc[i];
  }
  __syncthreads();

  const int x = tid & 15;
  const int c0 = tid >> 4;          // 0..63
  const int cell0 = blockIdx.x * GB_CELLS;
  const int b = cell0 >> 14;
  const int yx0 = cell0 & 16383;
  if (flags[0]) {
    bf16* o = (bf16*)out;
    o[(size_t)(b * C_ + c0) * (NY_ * NX_) + yx0 + x] = __float2bfloat16(s_out[x * 84 + c0]);
    if (c0 < 16)
      o[(size_t)(b * C_ + 64 + c0) * (NY_ * NX_) + yx0 + x] = __float2bfloat16(s_out[x * 84 + 64 + c0]);
  } else {
    float* o = (float*)out;
    o[(size_t)(b * C_ + c0) * (NY_ * NX_) + yx0 + x] = s_out[x * 84 + c0];
    if (c0 < 16)
      o[(size_t)(b * C_ + 64 + c0) * (NY_ * NX_) + yx0 + x] = s_out[x * 84 + 64 + c0];
  }
}

extern "C" void kernel_launch(void* const* d_in, const int* in_sizes, int n_in,
                              void* d_out, int out_size, void* d_ws, size_t ws_size,
                              hipStream_t stream) {
  const void* ctx = d_in[0];
  const void* logits = d_in[1];
  const void* s2e = d_in[2];
  const void* intrin = d_in[3];
  const void* ida = d_in[4];
  const void* bda = d_in[5];

  float* wsf = (float*)d_ws;
  int* flags   = (int*)wsf;                 // [0],[1] flags
  float* mats  = wsf + 16;                  // 384 floats used
  int* counts  = (int*)(wsf + 512);
  int* offsets = counts + NCELL;
  int* cursors = offsets + NCELL;
  float* ctx_t = (float*)(cursors + NCELL); // NCOL*C floats
  float* wts   = ctx_t + NCOL * C_;         // MAXT floats
  u16* colids  = (u16*)(wts + MAXT);        // MAXT u16

  lss_prep<<<33, 256, 0, stream>>>(logits, s2e, intrin, ida, bda, mats, flags, counts);
  lss_count<<<NCB + NTB, 256, 0, stream>>>(ctx, mats, flags, counts, ctx_t);
  lss_scan<<<1, 1024, 0, stream>>>(counts, offsets, cursors);
  lss_fill<<<NCOL, 64, 0, stream>>>(logits, mats, flags, cursors, colids, wts);
  lss_gather<<<NCELL / GB_CELLS, 1024, 0, stream>>>(ctx_t, counts, offsets, colids, wts, flags, d_out);
}